// Round 11
// baseline (365.374 us; speedup 1.0000x reference)
//
#include <hip/hip_runtime.h>
#include <hip/hip_bf16.h>
#include <stdint.h>

typedef _Float16 h16;
typedef h16 h16x2 __attribute__((ext_vector_type(2)));
typedef h16 h16x8 __attribute__((ext_vector_type(8)));
typedef float f32x4 __attribute__((ext_vector_type(4)));

#define HF 128          // hidden/feature dim
#define EPS 1e-5f
#define BSH 8           // bucket shift: 256 rows per bucket (196 buckets)
#define BROWS 256
#define BCAP 8192       // fixed bucket capacity (mean fill 4352, sigma ~66 -> huge margin)
#define ECHUNK 1024     // edges per workgroup in scatter (831 blocks -> more concurrency)
#define SBANKS 16       // stats atomic banks (784 blocks / 16 -> ~49 serialized per slot)

union pk32 { uint32_t u; h16x2 h; };

static __device__ __forceinline__ uint32_t pack_h16(float a, float b) {
    pk32 c;
    c.h[0] = (h16)a; c.h[1] = (h16)b;
    return c.u;
}

static __device__ __forceinline__ float sum8(const float* __restrict__ st, int idx) {
    float s = 0.f;
#pragma unroll
    for (int b = 0; b < SBANKS; b++) s += st[b * 256 + idx];
    return s;
}

// ---------------- prep (W swizzle + feats->fp16) MERGED with bucket scatter ----------
// blocks [0, ebk): edge scatter into buckets (packed 4B: src | row_in_bucket<<16)
// blocks [ebk, ebk+384): W transpose+swizzle fp16
// blocks [ebk+384, ...): feats fp32 -> packed fp16
// Two-phase bucketed staging is essential: direct row-cursor scatter costs a full
// 64B line per random 4B write (R7: 56MB WRITE for 3.4MB payload, 67us).
// fp16 payload is the floor: fp8 e4m3 gather tables fail absmax (R9: 1.19 > 0.34).
__global__ __launch_bounds__(256) void k_prepscat(const float* __restrict__ W1,
                                                  const float* __restrict__ W2,
                                                  h16* __restrict__ wp,
                                                  const float* __restrict__ feats,
                                                  uint32_t* __restrict__ hbuf, long tot2,
                                                  const int* __restrict__ src,
                                                  const int* __restrict__ dst,
                                                  int* __restrict__ gcursor,
                                                  uint32_t* __restrict__ staging, int ne, int nb,
                                                  int ebk) {
    __shared__ int h[256], gb[256];
    const int bid = (int)blockIdx.x;
    const int tid = threadIdx.x;
    if (bid < ebk) {
        // ---- bucket scatter ----
        if (tid < nb) h[tid] = 0;
        __syncthreads();
        const int beg = bid * ECHUNK;
        const int end = min(beg + ECHUNK, ne);
        for (int i = beg + tid; i < end; i += 256)
            atomicAdd(&h[dst[i] >> BSH], 1);
        __syncthreads();
        if (tid < nb) {
            int c = h[tid];
            gb[tid] = c ? atomicAdd(&gcursor[tid], c) : 0;   // within-bucket offset
            h[tid] = 0;
        }
        __syncthreads();
        for (int i = beg + tid; i < end; i += 256) {
            int d = dst[i];
            int b = d >> BSH;
            int r = atomicAdd(&h[b], 1);
            staging[(size_t)b * BCAP + gb[b] + r] =
                (uint32_t)src[i] | ((uint32_t)(d & (BROWS - 1)) << 16);
        }
    } else if (bid < ebk + 384) {
        // ---- W transpose + swizzle: (col r, k) -> r*128 + ((k>>3)^(r&7))*8 + (k&7) ----
        const int wb = bid - ebk;
        const int mat = wb >> 6;                          // 0..5
        const int idx = ((wb & 63) << 8) + tid;
        const int l = mat >> 1;
        const float* Wsrc = (mat & 1) ? (W2 + l * 16384) : (W1 + l * 16384);
        const int nn = idx >> 7, k = idx & 127;
        float w = Wsrc[k * 128 + nn];
        int pos = nn * 128 + ((((k >> 3) ^ (nn & 7))) << 3) + (k & 7);
        wp[mat * 16384 + pos] = (h16)w;
    } else {
        long i = (long)(bid - ebk - 384) * 256 + tid;
        if (i < tot2) {
            float2 v = ((const float2*)feats)[i];
            hbuf[i] = pack_h16(v.x, v.y);
        }
    }
}

// ---------------- bucket -> CSR (packed 4B staging entries, 256 rows/bucket) --------
__global__ __launch_bounds__(256) void k_bbuild(const uint32_t* __restrict__ staging,
                                                const int* __restrict__ gcursor,
                                                int* __restrict__ rowbeg,
                                                int* __restrict__ rowend,
                                                float* __restrict__ deginv,
                                                int* __restrict__ csrsrc, int n) {
    __shared__ int hist[BROWS];
    __shared__ int scan[BROWS];
    const int b = blockIdx.x;
    const int tid = threadIdx.x;
    const int rb = b << BSH;
    const int nrows = min(BROWS, n - rb);
    const int base = b * BCAP;
    const int cnt = gcursor[b];
    hist[tid] = 0;
    __syncthreads();
    for (int i = tid; i < cnt; i += 256)
        atomicAdd(&hist[staging[base + i] >> 16], 1);
    __syncthreads();
    const int d0 = hist[tid];
    scan[tid] = d0;
    __syncthreads();
    for (int off = 1; off < BROWS; off <<= 1) {
        int v = (tid >= off) ? scan[tid - off] : 0;
        __syncthreads();
        scan[tid] += v;
        __syncthreads();
    }
    {
        int excl = scan[tid] - d0;
        if (tid < nrows) {
            rowbeg[rb + tid] = base + excl;
            rowend[rb + tid] = base + excl + d0;
            deginv[rb + tid] = d0 ? 1.0f / (float)d0 : 0.f;
        }
        scan[tid] = excl;
    }
    __syncthreads();
    for (int i = tid; i < cnt; i += 256) {
        uint32_t e = staging[base + i];
        int pos = atomicAdd(&scan[e >> 16], 1);
        csrsrc[base + pos] = (int)(e & 0xFFFFu);
    }
}

// ---------------- SpMM: pooled = mean-gather(op(h)), 4-edges-per-load fp16 ----------
// One wave per dst row. 16-lane groups each gather a FULL 256B source row with one
// dwordx4 per lane. Up to 8 groups (32 edges) in flight. KEEP max occupancy / zero
// LDS: gather rate is per-CU outstanding-miss-limited (R5: fusing into 64-row tiles
// dropped occupancy 66->18% and halved fetch rate). The 82.7MB FETCH is the
// compulsory per-XCD refill of the gather table (random-line L3 path ~1.8 TB/s).
template <int AFF>
__global__ __launch_bounds__(256) void k_spmm(const uint32_t* __restrict__ hp,
                                              const int* __restrict__ rowbeg,
                                              const int* __restrict__ rowend,
                                              const float* __restrict__ deginv,
                                              const float* __restrict__ st,
                                              const float* __restrict__ g,
                                              const float* __restrict__ be,
                                              float inv_n,
                                              const int* __restrict__ csrsrc,
                                              uint32_t* __restrict__ pooled, int n, int np) {
    const int wid  = (int)((blockIdx.x * 256u + threadIdx.x) >> 6);
    const int lane = threadIdx.x & 63;
    if (wid >= np) return;
    const int gg = lane >> 4;     // edge subgroup 0..3
    const int fl = lane & 15;     // 16B feature slice within row
    uint4* outrow = (uint4*)(pooled + (size_t)wid * 64);
    if (wid >= n) {               // zero pad rows
        if (gg == 0) outrow[fl] = make_uint4(0u, 0u, 0u, 0u);
        return;
    }

    uint32_t sv[4], cv[4];
    if (AFF) {
        const int c0 = lane * 2, c1 = c0 + 1;
        float m0 = sum8(st, c0) * inv_n, v0 = sum8(st, 128 + c0) * inv_n - m0 * m0;
        float sx = g[c0] * rsqrtf(v0 + EPS), cx = be[c0] - m0 * sx;
        float m1 = sum8(st, c1) * inv_n, v1 = sum8(st, 128 + c1) * inv_n - m1 * m1;
        float sy = g[c1] * rsqrtf(v1 + EPS), cy = be[c1] - m1 * sy;
        uint32_t su = pack_h16(sx, sy);
        uint32_t cu = pack_h16(cx, cy);
#pragma unroll
        for (int w = 0; w < 4; w++) {
            sv[w] = (uint32_t)__shfl((int)su, fl * 4 + w);
            cv[w] = (uint32_t)__shfl((int)cu, fl * 4 + w);
        }
    }

    const h16 z0 = (h16)0.f;
    h16x2 acc[4];
#pragma unroll
    for (int w = 0; w < 4; w++) acc[w] = (h16x2)z0;

    const int beg = rowbeg[wid], end = rowend[wid];
    for (int base = beg; base < end; base += 64) {
        const int rem = end - base;
        const int cnt = rem < 64 ? rem : 64;
        const int off = lane < cnt ? lane : cnt - 1;
        const int idx = csrsrc[base + off];
        for (int j = 0; j < cnt; j += 32) {
            uint4 p[8];
#pragma unroll
            for (int u = 0; u < 8; u++) {
                const int eb = j + u * 4;
                if (eb < cnt) {
                    int ge = eb + gg;
                    int gec = ge < cnt ? ge : cnt - 1;
                    int s = __shfl(idx, gec);
                    p[u] = *(const uint4*)(hp + (size_t)s * 64 + (fl << 2));
                }
            }
#pragma unroll
            for (int u = 0; u < 8; u++) {
                const int eb = j + u * 4;
                if (eb < cnt) {
                    const uint32_t* pw = (const uint32_t*)&p[u];
                    h16x2 v[4];
#pragma unroll
                    for (int w = 0; w < 4; w++) {
                        pk32 t; t.u = pw[w];
                        h16x2 x = t.h;
                        if (AFF) {
                            pk32 s2; s2.u = sv[w];
                            pk32 c2; c2.u = cv[w];
                            x = x * s2.h + c2.h;
                            x[0] = x[0] > z0 ? x[0] : z0;
                            x[1] = x[1] > z0 ? x[1] : z0;
                        }
                        v[w] = x;
                    }
                    if (eb + gg < cnt) {
#pragma unroll
                        for (int w = 0; w < 4; w++) acc[w] = acc[w] + v[w];
                    }
                }
            }
        }
    }

#pragma unroll
    for (int w = 0; w < 4; w++) {
        pk32 t; t.h = acc[w];
        pk32 r1; r1.u = (uint32_t)__shfl_xor((int)t.u, 16);
        t.h = t.h + r1.h;
        pk32 r2; r2.u = (uint32_t)__shfl_xor((int)t.u, 32);
        t.h = t.h + r2.h;
        acc[w] = t.h;
    }

    const float di = deginv[wid];
    uint4 o;
    o.x = pack_h16((float)acc[0][0] * di, (float)acc[0][1] * di);
    o.y = pack_h16((float)acc[1][0] * di, (float)acc[1][1] * di);
    o.z = pack_h16((float)acc[2][0] * di, (float)acc[2][1] * di);
    o.w = pack_h16((float)acc[3][0] * di, (float)acc[3][1] * di);
    if (gg == 0) outrow[fl] = o;
}

// ---------------- GEMM: Y = op(A) @ W + bias, fp16 MFMA, fused banked column stats ----
// 64-row tile, 256 threads / 4 waves, grid = np/64 = 784 blocks, 4 blocks/CU.
template <int MODE>
__global__ __launch_bounds__(256) void k_gemm(const uint32_t* __restrict__ Ap,
                                              const h16* __restrict__ Wp,
                                              const float* __restrict__ bias,
                                              const float* __restrict__ st,
                                              const float* __restrict__ g,
                                              const float* __restrict__ be,
                                              float inv_n,
                                              h16* __restrict__ Y,
                                              float* __restrict__ outstats, int n) {
    __shared__ __align__(16) h16 WT[128 * 128];   // swizzled W^T, stride 128 (32 KB)
    __shared__ float sred[4][128];
    __shared__ float sred2[4][128];
    __shared__ float aff[256];
    const int tid = threadIdx.x;
    const int wave = tid >> 6, lane = tid & 63;

    // async DMA: 8 x (4 waves x 64 lanes x 16B) = 32 KB
    {
        const char* gsrc = (const char*)Wp + wave * 1024 + lane * 16;
        char* ldst = (char*)&WT[0] + wave * 1024;
#pragma unroll
        for (int i = 0; i < 8; i++) {
            __builtin_amdgcn_global_load_lds(
                (const __attribute__((address_space(1))) uint32_t*)(gsrc + i * 4096),
                (__attribute__((address_space(3))) uint32_t*)(ldst + i * 4096),
                16, 0, 0);
        }
    }
    if (MODE == 1 && tid < 128) {
        float m = sum8(st, tid) * inv_n;
        float v = sum8(st, 128 + tid) * inv_n - m * m;
        float a = g[tid] * rsqrtf(v + EPS);
        aff[tid] = a;
        aff[128 + tid] = be[tid] - m * a;
    }

    const int lrow = lane & 15, quad = lane >> 4;
    const int bx = (int)blockIdx.x * 64;
    const int mb = bx + wave * 16;        // this wave's 16 rows

    // A-fragment: A[m=lane&15][k=quad*8+j]; packed rows of 64 uint32
    h16x8 ah[4];
    uint4 araw[4];
    {
        const uint32_t* arow = Ap + (size_t)(mb + lrow) * 64 + quad * 4;
#pragma unroll
        for (int kt = 0; kt < 4; kt++)
            araw[kt] = *(const uint4*)(arow + kt * 16);
    }

    __syncthreads();   // drains DMA + aff visible

#pragma unroll
    for (int kt = 0; kt < 4; kt++) {
        if (MODE == 0) {
            ah[kt] = *(const h16x8*)&araw[kt];
        } else {
            const uint32_t* pw = (const uint32_t*)&araw[kt];
            h16x8 t;
#pragma unroll
            for (int j2 = 0; j2 < 4; j2++) {
                pk32 w; w.u = pw[j2];
                int k = kt * 32 + quad * 8 + j2 * 2;
                float x0 = fmaxf(fmaf((float)w.h[0], aff[k],     aff[128 + k]),     0.f);
                float x1 = fmaxf(fmaf((float)w.h[1], aff[k + 1], aff[129 + k]), 0.f);
                t[2 * j2]     = (h16)x0;
                t[2 * j2 + 1] = (h16)x1;
            }
            ah[kt] = t;
        }
    }

    f32x4 acc[8];
#pragma unroll
    for (int nt = 0; nt < 8; nt++) acc[nt] = (f32x4){0.f, 0.f, 0.f, 0.f};

    const int sw = lrow & 7;
#pragma unroll
    for (int nt = 0; nt < 8; nt++) {
        const h16* wbase = &WT[(nt * 16 + lrow) * 128];
#pragma unroll
        for (int kt = 0; kt < 4; kt++) {
            h16x8 bh = *(const h16x8*)(wbase + (((4 * kt + quad) ^ sw) << 3));
            acc[nt] = __builtin_amdgcn_mfma_f32_16x16x32_f16(ah[kt], bh, acc[nt], 0, 0, 0);
        }
    }

    // C/D layout: col = lane&15, row = quad*4 + reg  [verified m89]
#pragma unroll
    for (int nt = 0; nt < 8; nt++) {
        int col = nt * 16 + lrow;
        float bv = bias[col];
        float csum = 0.f, csq = 0.f;
#pragma unroll
        for (int r = 0; r < 4; r++) {
            int row = mb + quad * 4 + r;
            float yv = acc[nt][r] + bv;
            Y[(size_t)row * 128 + col] = (h16)yv;
            if (row < n) { csum += yv; csq += yv * yv; }
        }
        csum += __shfl_xor(csum, 16, 64); csum += __shfl_xor(csum, 32, 64);
        csq  += __shfl_xor(csq,  16, 64); csq  += __shfl_xor(csq,  32, 64);
        if (quad == 0) { sred[wave][col] = csum; sred2[wave][col] = csq; }
    }
    __syncthreads();
    if (tid < 128) {
        float s = sred[0][tid] + sred[1][tid] + sred[2][tid] + sred[3][tid];
        float q = sred2[0][tid] + sred2[1][tid] + sred2[2][tid] + sred2[3][tid];
        const int bank = (int)(blockIdx.x & (SBANKS - 1));
        atomicAdd(&outstats[bank * 256 + tid], s);
        atomicAdd(&outstats[bank * 256 + 128 + tid], q);
    }
}

// ---------------- final BN+ReLU: packed-fp16 z -> fp32 out, 16B/thread ----------
// affine table computed once per block in LDS (was: 64 stats loads + 4 rsqrt per thread)
__global__ __launch_bounds__(256) void k_bnrelu(const uint32_t* __restrict__ Z,
                                                const float* __restrict__ st,
                                                const float* __restrict__ g,
                                                const float* __restrict__ be,
                                                float inv_n,
                                                float* __restrict__ out, long tot4) {
    __shared__ float aff[256];
    const int tid = threadIdx.x;
    if (tid < 128) {
        float m = sum8(st, tid) * inv_n;
        float v = sum8(st, 128 + tid) * inv_n - m * m;
        float a = g[tid] * rsqrtf(v + EPS);
        aff[tid] = a;
        aff[128 + tid] = be[tid] - m * a;
    }
    __syncthreads();
    long i = (long)blockIdx.x * 256 + tid;           // i indexes a uint2 (4 h16 values)
    if (i >= tot4) return;
    int c = (int)((i * 4) & 127);
    uint2 w2 = ((const uint2*)Z)[i];
    pk32 w0; w0.u = w2.x;
    pk32 w1; w1.u = w2.y;
    float4 o;
    o.x = fmaxf(fmaf((float)w0.h[0], aff[c],     aff[128 + c]),     0.f);
    o.y = fmaxf(fmaf((float)w0.h[1], aff[c + 1], aff[129 + c]), 0.f);
    o.z = fmaxf(fmaf((float)w1.h[0], aff[c + 2], aff[130 + c]), 0.f);
    o.w = fmaxf(fmaf((float)w1.h[1], aff[c + 3], aff[131 + c]), 0.f);
    ((float4*)out)[i] = o;
}

// ---------------- launch ----------------
extern "C" void kernel_launch(void* const* d_in, const int* in_sizes, int n_in,
                              void* d_out, int out_size, void* d_ws, size_t ws_size,
                              hipStream_t stream) {
    const float* feats = (const float*)d_in[0];
    const float* W1    = (const float*)d_in[1];
    const float* b1    = (const float*)d_in[2];
    const float* g1    = (const float*)d_in[3];
    const float* be1   = (const float*)d_in[4];
    const float* W2    = (const float*)d_in[5];
    const float* b2    = (const float*)d_in[6];
    const float* og    = (const float*)d_in[7];
    const float* ob    = (const float*)d_in[8];
    const int*   src   = (const int*)d_in[9];
    const int*   dst   = (const int*)d_in[10];

    const int n  = in_sizes[0] / HF;         // 50000 nodes
    const int ne = in_sizes[9];              // 850000 edges (incl self loops)
    const int np = (n + 127) & ~127;         // pad to 128-row blocks
    const int nb = (n + BROWS - 1) >> BSH;   // 196 buckets (<=256)

    char* p = (char*)d_ws;
    auto alloc = [&](size_t bytes) -> char* {
        char* r = p;
        p += (bytes + 511) & ~(size_t)511;
        return r;
    };
    uint32_t* hbuf    = (uint32_t*)alloc((size_t)np * 64 * 4);    // packed fp16 feats/h
    uint32_t* pooled  = (uint32_t*)alloc((size_t)np * 64 * 4);    // packed fp16 pooled
    uint32_t* ybuf    = (uint32_t*)alloc((size_t)np * 64 * 4);    // packed fp16 y
    uint32_t* zb      = (uint32_t*)alloc((size_t)np * 64 * 4);    // packed fp16 z
    h16*      wprep   = (h16*)     alloc(6 * 16384 * 2);          // swizzled fp16 W^T x6
    float*    deginv  = (float*)   alloc((size_t)n * 4);
    int*      rowbeg  = (int*)     alloc((size_t)n * 4);
    int*      rowend  = (int*)     alloc((size_t)n * 4);
    int*      csrsrc  = (int*)     alloc((size_t)nb * BCAP * 4);
    uint32_t* staging = (uint32_t*)alloc((size_t)nb * BCAP * 4);  // packed 4B entries
    // zero zone: gcursor (nb ints) + 6 banked stats slots
    char*     zone    = alloc(1024 + 6 * SBANKS * 256 * 4);
    int*      gcursor = (int*)zone;
    float*    stats6  = (float*)(zone + 1024);

    hipMemsetAsync(zone, 0, 1024 + 6 * SBANKS * 256 * 4, stream);

    const long tot2  = (long)n * (HF / 2);
    const long tot4  = tot2 / 2;
    const int bnb    = (int)((tot2 + 255) / 256);
    const int bnb4   = (int)((tot4 + 255) / 256);
    const int spmmb  = np / 4;
    const int gemmb  = np / 64;
    const float inv_n = 1.0f / (float)n;
    const int ebk = (ne + ECHUNK - 1) / ECHUNK;
    const int SL = SBANKS * 256;

    k_prepscat<<<ebk + 384 + bnb, 256, 0, stream>>>(W1, W2, wprep, feats, hbuf, tot2,
                                                    src, dst, gcursor, staging, ne, nb, ebk);
    k_bbuild  <<<nb, 256, 0, stream>>>(staging, gcursor, rowbeg, rowend, deginv, csrsrc, n);

    for (int l = 0; l < 3; l++) {
        float* sY = stats6 + (2 * l) * SL;       // y-stats slot (banked)
        float* sZ = stats6 + (2 * l + 1) * SL;   // z-stats slot (banked)
        if (l == 0)
            k_spmm<0><<<spmmb, 256, 0, stream>>>(hbuf, rowbeg, rowend, deginv,
                                                 nullptr, nullptr, nullptr, inv_n,
                                                 csrsrc, pooled, n, np);
        else
            k_spmm<1><<<spmmb, 256, 0, stream>>>(zb, rowbeg, rowend, deginv,
                                                 stats6 + (2 * (l - 1) + 1) * SL,
                                                 og + (l - 1) * HF, ob + (l - 1) * HF, inv_n,
                                                 csrsrc, pooled, n, np);
        k_gemm<0><<<gemmb, 256, 0, stream>>>(pooled,
                                             wprep + (size_t)(2 * l) * 16384,
                                             b1 + l * HF,
                                             nullptr, nullptr, nullptr, inv_n,
                                             (h16*)ybuf, sY, n);
        k_gemm<1><<<gemmb, 256, 0, stream>>>(ybuf,
                                             wprep + (size_t)(2 * l + 1) * 16384,
                                             b2 + l * HF,
                                             sY, g1 + l * HF, be1 + l * HF, inv_n,
                                             (h16*)zb, sZ, n);
    }
    k_bnrelu<<<bnb4, 256, 0, stream>>>(zb, stats6 + 5 * SL, og + 2 * HF, ob + 2 * HF,
                                       inv_n, (float*)d_out, tot4);
}

// Round 12
// 327.016 us; speedup vs baseline: 1.1173x; 1.1173x over previous
//
#include <hip/hip_runtime.h>
#include <hip/hip_bf16.h>
#include <stdint.h>

typedef _Float16 h16;
typedef h16 h16x2 __attribute__((ext_vector_type(2)));
typedef h16 h16x8 __attribute__((ext_vector_type(8)));
typedef float f32x4 __attribute__((ext_vector_type(4)));

#define HF 128          // hidden/feature dim
#define EPS 1e-5f
#define BSH 8           // bucket shift: 256 rows per bucket (196 buckets)
#define BROWS 256
#define BCAP 8192       // fixed bucket capacity (mean fill 4352, sigma ~66 -> huge margin)
#define ECHUNK 2048     // edges per workgroup in scatter (416 blocks)
#define SBANKS 8        // stats atomic banks (R11: 16 banks perturbed spmm codegen, -11%)

union pk32 { uint32_t u; h16x2 h; };

static __device__ __forceinline__ uint32_t pack_h16(float a, float b) {
    pk32 c;
    c.h[0] = (h16)a; c.h[1] = (h16)b;
    return c.u;
}

static __device__ __forceinline__ float sum8(const float* __restrict__ st, int idx) {
    float s = 0.f;
#pragma unroll
    for (int b = 0; b < SBANKS; b++) s += st[b * 256 + idx];
    return s;
}

// ---------------- prep (W swizzle + feats->fp16) MERGED with bucket scatter ----------
// blocks [0, ebk): edge scatter into buckets (packed 4B: src | row_in_bucket<<16)
// blocks [ebk, ebk+384): W transpose+swizzle fp16
// blocks [ebk+384, ...): feats fp32 -> packed fp16
// Two-phase bucketed staging is essential: direct row-cursor scatter costs a full
// 64B line per random 4B write (R7: 56MB WRITE for 3.4MB payload, 67us).
// fp16 payload is the floor: fp8 e4m3 gather tables fail absmax (R9: 1.19 > 0.34).
__global__ __launch_bounds__(256) void k_prepscat(const float* __restrict__ W1,
                                                  const float* __restrict__ W2,
                                                  h16* __restrict__ wp,
                                                  const float* __restrict__ feats,
                                                  uint32_t* __restrict__ hbuf, long tot2,
                                                  const int* __restrict__ src,
                                                  const int* __restrict__ dst,
                                                  int* __restrict__ gcursor,
                                                  uint32_t* __restrict__ staging, int ne, int nb,
                                                  int ebk) {
    __shared__ int h[256], gb[256];
    const int bid = (int)blockIdx.x;
    const int tid = threadIdx.x;
    if (bid < ebk) {
        // ---- bucket scatter ----
        if (tid < nb) h[tid] = 0;
        __syncthreads();
        const int beg = bid * ECHUNK;
        const int end = min(beg + ECHUNK, ne);
        for (int i = beg + tid; i < end; i += 256)
            atomicAdd(&h[dst[i] >> BSH], 1);
        __syncthreads();
        if (tid < nb) {
            int c = h[tid];
            gb[tid] = c ? atomicAdd(&gcursor[tid], c) : 0;   // within-bucket offset
            h[tid] = 0;
        }
        __syncthreads();
        for (int i = beg + tid; i < end; i += 256) {
            int d = dst[i];
            int b = d >> BSH;
            int r = atomicAdd(&h[b], 1);
            staging[(size_t)b * BCAP + gb[b] + r] =
                (uint32_t)src[i] | ((uint32_t)(d & (BROWS - 1)) << 16);
        }
    } else if (bid < ebk + 384) {
        // ---- W transpose + swizzle: (col r, k) -> r*128 + ((k>>3)^(r&7))*8 + (k&7) ----
        const int wb = bid - ebk;
        const int mat = wb >> 6;                          // 0..5
        const int idx = ((wb & 63) << 8) + tid;
        const int l = mat >> 1;
        const float* Wsrc = (mat & 1) ? (W2 + l * 16384) : (W1 + l * 16384);
        const int nn = idx >> 7, k = idx & 127;
        float w = Wsrc[k * 128 + nn];
        int pos = nn * 128 + ((((k >> 3) ^ (nn & 7))) << 3) + (k & 7);
        wp[mat * 16384 + pos] = (h16)w;
    } else {
        long i = (long)(bid - ebk - 384) * 256 + tid;
        if (i < tot2) {
            float2 v = ((const float2*)feats)[i];
            hbuf[i] = pack_h16(v.x, v.y);
        }
    }
}

// ---------------- bucket -> CSR (packed 4B staging entries, 256 rows/bucket) --------
__global__ __launch_bounds__(256) void k_bbuild(const uint32_t* __restrict__ staging,
                                                const int* __restrict__ gcursor,
                                                int* __restrict__ rowbeg,
                                                int* __restrict__ rowend,
                                                float* __restrict__ deginv,
                                                int* __restrict__ csrsrc, int n) {
    __shared__ int hist[BROWS];
    __shared__ int scan[BROWS];
    const int b = blockIdx.x;
    const int tid = threadIdx.x;
    const int rb = b << BSH;
    const int nrows = min(BROWS, n - rb);
    const int base = b * BCAP;
    const int cnt = gcursor[b];
    hist[tid] = 0;
    __syncthreads();
    for (int i = tid; i < cnt; i += 256)
        atomicAdd(&hist[staging[base + i] >> 16], 1);
    __syncthreads();
    const int d0 = hist[tid];
    scan[tid] = d0;
    __syncthreads();
    for (int off = 1; off < BROWS; off <<= 1) {
        int v = (tid >= off) ? scan[tid - off] : 0;
        __syncthreads();
        scan[tid] += v;
        __syncthreads();
    }
    {
        int excl = scan[tid] - d0;
        if (tid < nrows) {
            rowbeg[rb + tid] = base + excl;
            rowend[rb + tid] = base + excl + d0;
            deginv[rb + tid] = d0 ? 1.0f / (float)d0 : 0.f;
        }
        scan[tid] = excl;
    }
    __syncthreads();
    for (int i = tid; i < cnt; i += 256) {
        uint32_t e = staging[base + i];
        int pos = atomicAdd(&scan[e >> 16], 1);
        csrsrc[base + pos] = (int)(e & 0xFFFFu);
    }
}

// ---------------- SpMM: pooled = mean-gather(op(h)), 4-edges-per-load fp16 ----------
// One wave per dst row. 16-lane groups each gather a FULL 256B source row with one
// dwordx4 per lane. Up to 8 groups (32 edges) in flight. KEEP max occupancy / zero
// LDS: gather rate is per-CU outstanding-miss-limited (R5: fusing into 64-row tiles
// dropped occupancy 66->18% and halved fetch rate). The 82.7MB FETCH is the
// compulsory per-XCD refill of the gather table (random-line L3 path ~1.8 TB/s).
template <int AFF>
__global__ __launch_bounds__(256) void k_spmm(const uint32_t* __restrict__ hp,
                                              const int* __restrict__ rowbeg,
                                              const int* __restrict__ rowend,
                                              const float* __restrict__ deginv,
                                              const float* __restrict__ st,
                                              const float* __restrict__ g,
                                              const float* __restrict__ be,
                                              float inv_n,
                                              const int* __restrict__ csrsrc,
                                              uint32_t* __restrict__ pooled, int n, int np) {
    const int wid  = (int)((blockIdx.x * 256u + threadIdx.x) >> 6);
    const int lane = threadIdx.x & 63;
    if (wid >= np) return;
    const int gg = lane >> 4;     // edge subgroup 0..3
    const int fl = lane & 15;     // 16B feature slice within row
    uint4* outrow = (uint4*)(pooled + (size_t)wid * 64);
    if (wid >= n) {               // zero pad rows
        if (gg == 0) outrow[fl] = make_uint4(0u, 0u, 0u, 0u);
        return;
    }

    uint32_t sv[4], cv[4];
    if (AFF) {
        const int c0 = lane * 2, c1 = c0 + 1;
        float m0 = sum8(st, c0) * inv_n, v0 = sum8(st, 128 + c0) * inv_n - m0 * m0;
        float sx = g[c0] * rsqrtf(v0 + EPS), cx = be[c0] - m0 * sx;
        float m1 = sum8(st, c1) * inv_n, v1 = sum8(st, 128 + c1) * inv_n - m1 * m1;
        float sy = g[c1] * rsqrtf(v1 + EPS), cy = be[c1] - m1 * sy;
        uint32_t su = pack_h16(sx, sy);
        uint32_t cu = pack_h16(cx, cy);
#pragma unroll
        for (int w = 0; w < 4; w++) {
            sv[w] = (uint32_t)__shfl((int)su, fl * 4 + w);
            cv[w] = (uint32_t)__shfl((int)cu, fl * 4 + w);
        }
    }

    const h16 z0 = (h16)0.f;
    h16x2 acc[4];
#pragma unroll
    for (int w = 0; w < 4; w++) acc[w] = (h16x2)z0;

    const int beg = rowbeg[wid], end = rowend[wid];
    for (int base = beg; base < end; base += 64) {
        const int rem = end - base;
        const int cnt = rem < 64 ? rem : 64;
        const int off = lane < cnt ? lane : cnt - 1;
        const int idx = csrsrc[base + off];
        for (int j = 0; j < cnt; j += 32) {
            uint4 p[8];
#pragma unroll
            for (int u = 0; u < 8; u++) {
                const int eb = j + u * 4;
                if (eb < cnt) {
                    int ge = eb + gg;
                    int gec = ge < cnt ? ge : cnt - 1;
                    int s = __shfl(idx, gec);
                    p[u] = *(const uint4*)(hp + (size_t)s * 64 + (fl << 2));
                }
            }
#pragma unroll
            for (int u = 0; u < 8; u++) {
                const int eb = j + u * 4;
                if (eb < cnt) {
                    const uint32_t* pw = (const uint32_t*)&p[u];
                    h16x2 v[4];
#pragma unroll
                    for (int w = 0; w < 4; w++) {
                        pk32 t; t.u = pw[w];
                        h16x2 x = t.h;
                        if (AFF) {
                            pk32 s2; s2.u = sv[w];
                            pk32 c2; c2.u = cv[w];
                            x = x * s2.h + c2.h;
                            x[0] = x[0] > z0 ? x[0] : z0;
                            x[1] = x[1] > z0 ? x[1] : z0;
                        }
                        v[w] = x;
                    }
                    if (eb + gg < cnt) {
#pragma unroll
                        for (int w = 0; w < 4; w++) acc[w] = acc[w] + v[w];
                    }
                }
            }
        }
    }

#pragma unroll
    for (int w = 0; w < 4; w++) {
        pk32 t; t.h = acc[w];
        pk32 r1; r1.u = (uint32_t)__shfl_xor((int)t.u, 16);
        t.h = t.h + r1.h;
        pk32 r2; r2.u = (uint32_t)__shfl_xor((int)t.u, 32);
        t.h = t.h + r2.h;
        acc[w] = t.h;
    }

    const float di = deginv[wid];
    uint4 o;
    o.x = pack_h16((float)acc[0][0] * di, (float)acc[0][1] * di);
    o.y = pack_h16((float)acc[1][0] * di, (float)acc[1][1] * di);
    o.z = pack_h16((float)acc[2][0] * di, (float)acc[2][1] * di);
    o.w = pack_h16((float)acc[3][0] * di, (float)acc[3][1] * di);
    if (gg == 0) outrow[fl] = o;
}

// ---------------- GEMM: Y = op(A) @ W + bias, fp16 MFMA, fused banked column stats ----
// 64-row tile, 256 threads / 4 waves, grid = np/64 = 784 blocks, 4 blocks/CU.
template <int MODE>
__global__ __launch_bounds__(256) void k_gemm(const uint32_t* __restrict__ Ap,
                                              const h16* __restrict__ Wp,
                                              const float* __restrict__ bias,
                                              const float* __restrict__ st,
                                              const float* __restrict__ g,
                                              const float* __restrict__ be,
                                              float inv_n,
                                              h16* __restrict__ Y,
                                              float* __restrict__ outstats, int n) {
    __shared__ __align__(16) h16 WT[128 * 128];   // swizzled W^T, stride 128 (32 KB)
    __shared__ float sred[4][128];
    __shared__ float sred2[4][128];
    __shared__ float aff[256];
    const int tid = threadIdx.x;
    const int wave = tid >> 6, lane = tid & 63;

    // async DMA: 8 x (4 waves x 64 lanes x 16B) = 32 KB
    {
        const char* gsrc = (const char*)Wp + wave * 1024 + lane * 16;
        char* ldst = (char*)&WT[0] + wave * 1024;
#pragma unroll
        for (int i = 0; i < 8; i++) {
            __builtin_amdgcn_global_load_lds(
                (const __attribute__((address_space(1))) uint32_t*)(gsrc + i * 4096),
                (__attribute__((address_space(3))) uint32_t*)(ldst + i * 4096),
                16, 0, 0);
        }
    }
    if (MODE == 1 && tid < 128) {
        float m = sum8(st, tid) * inv_n;
        float v = sum8(st, 128 + tid) * inv_n - m * m;
        float a = g[tid] * rsqrtf(v + EPS);
        aff[tid] = a;
        aff[128 + tid] = be[tid] - m * a;
    }

    const int lrow = lane & 15, quad = lane >> 4;
    const int bx = (int)blockIdx.x * 64;
    const int mb = bx + wave * 16;        // this wave's 16 rows

    // A-fragment: A[m=lane&15][k=quad*8+j]; packed rows of 64 uint32
    h16x8 ah[4];
    uint4 araw[4];
    {
        const uint32_t* arow = Ap + (size_t)(mb + lrow) * 64 + quad * 4;
#pragma unroll
        for (int kt = 0; kt < 4; kt++)
            araw[kt] = *(const uint4*)(arow + kt * 16);
    }

    __syncthreads();   // drains DMA + aff visible

#pragma unroll
    for (int kt = 0; kt < 4; kt++) {
        if (MODE == 0) {
            ah[kt] = *(const h16x8*)&araw[kt];
        } else {
            const uint32_t* pw = (const uint32_t*)&araw[kt];
            h16x8 t;
#pragma unroll
            for (int j2 = 0; j2 < 4; j2++) {
                pk32 w; w.u = pw[j2];
                int k = kt * 32 + quad * 8 + j2 * 2;
                float x0 = fmaxf(fmaf((float)w.h[0], aff[k],     aff[128 + k]),     0.f);
                float x1 = fmaxf(fmaf((float)w.h[1], aff[k + 1], aff[129 + k]), 0.f);
                t[2 * j2]     = (h16)x0;
                t[2 * j2 + 1] = (h16)x1;
            }
            ah[kt] = t;
        }
    }

    f32x4 acc[8];
#pragma unroll
    for (int nt = 0; nt < 8; nt++) acc[nt] = (f32x4){0.f, 0.f, 0.f, 0.f};

    const int sw = lrow & 7;
#pragma unroll
    for (int nt = 0; nt < 8; nt++) {
        const h16* wbase = &WT[(nt * 16 + lrow) * 128];
#pragma unroll
        for (int kt = 0; kt < 4; kt++) {
            h16x8 bh = *(const h16x8*)(wbase + (((4 * kt + quad) ^ sw) << 3));
            acc[nt] = __builtin_amdgcn_mfma_f32_16x16x32_f16(ah[kt], bh, acc[nt], 0, 0, 0);
        }
    }

    // C/D layout: col = lane&15, row = quad*4 + reg  [verified m89]
#pragma unroll
    for (int nt = 0; nt < 8; nt++) {
        int col = nt * 16 + lrow;
        float bv = bias[col];
        float csum = 0.f, csq = 0.f;
#pragma unroll
        for (int r = 0; r < 4; r++) {
            int row = mb + quad * 4 + r;
            float yv = acc[nt][r] + bv;
            Y[(size_t)row * 128 + col] = (h16)yv;
            if (row < n) { csum += yv; csq += yv * yv; }
        }
        csum += __shfl_xor(csum, 16, 64); csum += __shfl_xor(csum, 32, 64);
        csq  += __shfl_xor(csq,  16, 64); csq  += __shfl_xor(csq,  32, 64);
        if (quad == 0) { sred[wave][col] = csum; sred2[wave][col] = csq; }
    }
    __syncthreads();
    if (tid < 128) {
        float s = sred[0][tid] + sred[1][tid] + sred[2][tid] + sred[3][tid];
        float q = sred2[0][tid] + sred2[1][tid] + sred2[2][tid] + sred2[3][tid];
        const int bank = (int)(blockIdx.x & (SBANKS - 1));
        atomicAdd(&outstats[bank * 256 + tid], s);
        atomicAdd(&outstats[bank * 256 + 128 + tid], q);
    }
}

// ---------------- final BN+ReLU: packed-fp16 z -> fp32 out, 16B/thread ----------
__global__ __launch_bounds__(256) void k_bnrelu(const uint32_t* __restrict__ Z,
                                                const float* __restrict__ st,
                                                const float* __restrict__ g,
                                                const float* __restrict__ be,
                                                float inv_n,
                                                float* __restrict__ out, long tot4) {
    long i = (long)blockIdx.x * 256 + threadIdx.x;   // i indexes a uint2 (4 h16 values)
    if (i >= tot4) return;
    int c = (int)((i * 4) & 127);
    float a[4], cc[4];
#pragma unroll
    for (int j = 0; j < 4; j++) {
        float m = sum8(st, c + j) * inv_n;
        float v = sum8(st, 128 + c + j) * inv_n - m * m;
        a[j] = g[c + j] * rsqrtf(v + EPS);
        cc[j] = be[c + j] - m * a[j];
    }
    uint2 w2 = ((const uint2*)Z)[i];
    pk32 w0; w0.u = w2.x;
    pk32 w1; w1.u = w2.y;
    float4 o;
    o.x = fmaxf(fmaf((float)w0.h[0], a[0], cc[0]), 0.f);
    o.y = fmaxf(fmaf((float)w0.h[1], a[1], cc[1]), 0.f);
    o.z = fmaxf(fmaf((float)w1.h[0], a[2], cc[2]), 0.f);
    o.w = fmaxf(fmaf((float)w1.h[1], a[3], cc[3]), 0.f);
    ((float4*)out)[i] = o;
}

// ---------------- launch ----------------
extern "C" void kernel_launch(void* const* d_in, const int* in_sizes, int n_in,
                              void* d_out, int out_size, void* d_ws, size_t ws_size,
                              hipStream_t stream) {
    const float* feats = (const float*)d_in[0];
    const float* W1    = (const float*)d_in[1];
    const float* b1    = (const float*)d_in[2];
    const float* g1    = (const float*)d_in[3];
    const float* be1   = (const float*)d_in[4];
    const float* W2    = (const float*)d_in[5];
    const float* b2    = (const float*)d_in[6];
    const float* og    = (const float*)d_in[7];
    const float* ob    = (const float*)d_in[8];
    const int*   src   = (const int*)d_in[9];
    const int*   dst   = (const int*)d_in[10];

    const int n  = in_sizes[0] / HF;         // 50000 nodes
    const int ne = in_sizes[9];              // 850000 edges (incl self loops)
    const int np = (n + 127) & ~127;         // pad to 128-row blocks
    const int nb = (n + BROWS - 1) >> BSH;   // 196 buckets (<=256)

    char* p = (char*)d_ws;
    auto alloc = [&](size_t bytes) -> char* {
        char* r = p;
        p += (bytes + 511) & ~(size_t)511;
        return r;
    };
    uint32_t* hbuf    = (uint32_t*)alloc((size_t)np * 64 * 4);    // packed fp16 feats/h
    uint32_t* pooled  = (uint32_t*)alloc((size_t)np * 64 * 4);    // packed fp16 pooled
    uint32_t* ybuf    = (uint32_t*)alloc((size_t)np * 64 * 4);    // packed fp16 y
    uint32_t* zb      = (uint32_t*)alloc((size_t)np * 64 * 4);    // packed fp16 z
    h16*      wprep   = (h16*)     alloc(6 * 16384 * 2);          // swizzled fp16 W^T x6
    float*    deginv  = (float*)   alloc((size_t)n * 4);
    int*      rowbeg  = (int*)     alloc((size_t)n * 4);
    int*      rowend  = (int*)     alloc((size_t)n * 4);
    int*      csrsrc  = (int*)     alloc((size_t)nb * BCAP * 4);
    uint32_t* staging = (uint32_t*)alloc((size_t)nb * BCAP * 4);  // packed 4B entries
    // zero zone: gcursor (nb ints) + 6 banked stats slots
    char*     zone    = alloc(1024 + 6 * SBANKS * 256 * 4);
    int*      gcursor = (int*)zone;
    float*    stats6  = (float*)(zone + 1024);

    hipMemsetAsync(zone, 0, 1024 + 6 * SBANKS * 256 * 4, stream);

    const long tot2  = (long)n * (HF / 2);
    const long tot4  = tot2 / 2;
    const int bnb    = (int)((tot2 + 255) / 256);
    const int bnb4   = (int)((tot4 + 255) / 256);
    const int spmmb  = np / 4;
    const int gemmb  = np / 64;
    const float inv_n = 1.0f / (float)n;
    const int ebk = (ne + ECHUNK - 1) / ECHUNK;
    const int SL = SBANKS * 256;

    k_prepscat<<<ebk + 384 + bnb, 256, 0, stream>>>(W1, W2, wprep, feats, hbuf, tot2,
                                                    src, dst, gcursor, staging, ne, nb, ebk);
    k_bbuild  <<<nb, 256, 0, stream>>>(staging, gcursor, rowbeg, rowend, deginv, csrsrc, n);

    for (int l = 0; l < 3; l++) {
        float* sY = stats6 + (2 * l) * SL;       // y-stats slot (banked)
        float* sZ = stats6 + (2 * l + 1) * SL;   // z-stats slot (banked)
        if (l == 0)
            k_spmm<0><<<spmmb, 256, 0, stream>>>(hbuf, rowbeg, rowend, deginv,
                                                 nullptr, nullptr, nullptr, inv_n,
                                                 csrsrc, pooled, n, np);
        else
            k_spmm<1><<<spmmb, 256, 0, stream>>>(zb, rowbeg, rowend, deginv,
                                                 stats6 + (2 * (l - 1) + 1) * SL,
                                                 og + (l - 1) * HF, ob + (l - 1) * HF, inv_n,
                                                 csrsrc, pooled, n, np);
        k_gemm<0><<<gemmb, 256, 0, stream>>>(pooled,
                                             wprep + (size_t)(2 * l) * 16384,
                                             b1 + l * HF,
                                             nullptr, nullptr, nullptr, inv_n,
                                             (h16*)ybuf, sY, n);
        k_gemm<1><<<gemmb, 256, 0, stream>>>(ybuf,
                                             wprep + (size_t)(2 * l + 1) * 16384,
                                             b2 + l * HF,
                                             sY, g1 + l * HF, be1 + l * HF, inv_n,
                                             (h16*)zb, sZ, n);
    }
    k_bnrelu<<<bnb4, 256, 0, stream>>>(zb, stats6 + 5 * SL, og + 2 * HF, ob + 2 * HF,
                                       inv_n, (float*)d_out, tot4);
}